// Round 4
// baseline (163.035 us; speedup 1.0000x reference)
//
#include <hip/hip_runtime.h>

// SINDy: out[65536,32] = Theta(z)[65536,6545] @ (Xi*Xi_mask)[6545,32]
// Round-4: round-3 structure (augmented z~=(z,1), term = p(i,j)*z~[8q+jj],
// 4 static-q segments, B pre-packed to fragment order, 4-chunk register
// double-buffer) with the VALU trimmed:
//  - float2 packed products -> v_pk_mul_f32 (8 muls -> 4)
//  - merged u64 meta (one s_load_dwordx2 per chunk)
//  - #pragma unroll 2 group loop (regalloc ping-pong, no mov chains)
//  - prep kernel branchless via flat constexpr ROWTAB (kills rodata scatter)
// MFMA 32x32x16_bf16 layouts (verified rounds 1-3):
//   A[m][k]: m=lane&31, k=(lane>>5)*8+jj
//   B[k][n]: n=lane&31, k=(lane>>5)*8+jj
//   C/D:     col=lane&31, row=(reg&3)+8*(reg>>2)+4*(lane>>5)

#define Z 32
#define ROWS 65536
#define WPB 4
#define NBLK (ROWS / 32 / WPB)   // 512 blocks x 4 waves, one 32x32 tile per wave

#define NCHUNK 552               // 36 + 84 + 160 + 272 (each %4 == 0)
#define NGRAN (NCHUNK * 2)

typedef short short8 __attribute__((ext_vector_type(8)));
typedef float f32x16 __attribute__((ext_vector_type(16)));
typedef float float2v __attribute__((ext_vector_type(2)));

struct Sched {
    int nq[4];                       // chunks per quarter-segment
    unsigned long long m2[NCHUNK];   // lo32: granule0 (i*4)|(j*4)<<16 ; hi32: granule1
    short rt[NGRAN * 8];             // library row per (granule, jj), -1 = pad
};

constexpr Sched make_sched() {
    Sched s{};
    short gi[NGRAN] = {}, gj[NGRAN] = {};
    char gt[NGRAN] = {}, gq[NGRAN] = {};
    int tidx[32][32] = {}, pidx[32] = {};
    {
        int n = 0;
        for (int a = 0; a < 32; ++a)
            for (int b = a; b < 32; ++b) { tidx[a][b] = n; n += 32 - b; }
        for (int i = 0; i < 32; ++i) pidx[i] = i * 32 - i * (i - 1) / 2;
    }
    int g = 0;
    for (int q = 0; q < 4; ++q) {
        int g0 = g;
        // triples (a<=b): granule covers k in [8q,8q+8) for k>=b -> need b>>3 <= q
        for (int b = 0; b < 32; ++b)
            if ((b >> 3) <= q)
                for (int a = 0; a <= b; ++a) { gi[g]=(short)a; gj[g]=(short)b; gt[g]=0; gq[g]=(char)q; ++g; }
        // pairs (b,32): theta = z_b*z_k, valid k<=b -> need b>>3 >= q
        for (int b = 0; b < 32; ++b)
            if ((b >> 3) >= q) { gi[g]=(short)b; gj[g]=32; gt[g]=1; gq[g]=(char)q; ++g; }
        // linear: theta = z_k
        gi[g]=32; gj[g]=32; gt[g]=2; gq[g]=(char)q; ++g;
        // pad quarter to a multiple of 8 granules (4 chunks)
        while ((g - g0) & 7) { gi[g]=32; gj[g]=32; gt[g]=3; gq[g]=(char)q; ++g; }
        s.nq[q] = (g - g0) / 2;
    }
    for (int c = 0; c < NCHUNK; ++c) {
        unsigned lo = ((unsigned)gi[2*c]   * 4u) | (((unsigned)gj[2*c]   * 4u) << 16);
        unsigned hi = ((unsigned)gi[2*c+1] * 4u) | (((unsigned)gj[2*c+1] * 4u) << 16);
        s.m2[c] = (unsigned long long)lo | ((unsigned long long)hi << 32);
    }
    for (int gg = 0; gg < NGRAN; ++gg) {
        int i = gi[gg], j = gj[gg], ty = gt[gg], q = gq[gg];
        for (int jj = 0; jj < 8; ++jj) {
            int k = 8 * q + jj, row = -1;
            if (ty == 0)      { if (k >= j) row = 561 + tidx[i][j] + (k - j); }   // triple (i,j,k)
            else if (ty == 1) { if (k <= i) row = 33 + pidx[k] + (i - k); }       // pair (k,i)
            else if (ty == 2) { row = 1 + k; }                                    // linear z_k
            s.rt[gg * 8 + jj] = (short)row;
        }
    }
    return s;
}
constexpr Sched S = make_sched();
static_assert(S.nq[0] == 36 && S.nq[1] == 84 && S.nq[2] == 160 && S.nq[3] == 272, "chunk counts");

__device__ __forceinline__ unsigned pack_bf16(float s0, float s1) {
#if __has_builtin(__builtin_amdgcn_cvt_pk_bf16_f32)
    return __builtin_bit_cast(unsigned, __builtin_amdgcn_cvt_pk_bf16_f32(s0, s1));
#else
    unsigned b0 = __builtin_bit_cast(unsigned, s0) + 0x8000u;
    unsigned b1 = __builtin_bit_cast(unsigned, s1) + 0x8000u;
    return __builtin_amdgcn_perm(b1, b0, 0x07060302u);   // lo16=s0, hi16=s1
#endif
}

// ---- prep: pack Xi_eff (bf16 RNE) into granule-ordered B fragments ----
// Branchless: row index straight from flat ROWTAB (uniform per half-wave).
__global__ void sindy_prep(const float* __restrict__ Xi,
                           const float* __restrict__ Xi_mask,
                           uint4* __restrict__ Bp, size_t ws_size) {
    int tid = blockIdx.x * blockDim.x + threadIdx.x;
    if (tid >= NCHUNK * 64) return;
    if ((size_t)(tid + 1) * 16 > ws_size) return;   // safety
    int c = tid >> 6, l = tid & 63;
    int g = 2 * c + (l >> 5);
    int n = l & 31;
    const short* rt = &S.rt[g * 8];
    unsigned v[8];
#pragma unroll
    for (int jj = 0; jj < 8; ++jj) {
        int row = rt[jj];
        float f = 0.0f;
        if (row >= 0) f = Xi[row * Z + n] * Xi_mask[row * Z + n];
        unsigned u = __builtin_bit_cast(unsigned, f);
        v[jj] = (u + 0x7FFFu + ((u >> 16) & 1u)) >> 16;   // RNE to bf16
    }
    uint4 o;
    o.x = v[0] | (v[1] << 16);
    o.y = v[2] | (v[3] << 16);
    o.z = v[4] | (v[5] << 16);
    o.w = v[6] | (v[7] << 16);
    Bp[tid] = o;
}

// ---- 4-chunk compute body ----
template<int Q>
__device__ __forceinline__ void chunk4(int c, const uint4 (&bb)[4],
                                       const float2v (&zr2)[16],
                                       const char* zbase, bool hi, f32x16& acc) {
#pragma unroll
    for (int i = 0; i < 4; ++i) {
        unsigned long long m2 = S.m2[c + i];            // uniform -> s_load_dwordx2
        unsigned mw = hi ? (unsigned)(m2 >> 32) : (unsigned)m2;
        float zi = *(const float*)(zbase + (mw & 0xFFFFu));
        float zj = *(const float*)(zbase + (mw >> 16));
        float p = zi * zj;
        float2v p2 = {p, p};
        union { unsigned u[4]; short8 s; } a;
#pragma unroll
        for (int r = 0; r < 4; ++r) {
            float2v t = p2 * zr2[4 * Q + r];            // v_pk_mul_f32
            a.u[r] = pack_bf16(t.x, t.y);
        }
        union { uint4 v; short8 s; } b; b.v = bb[i];
        acc = __builtin_amdgcn_mfma_f32_32x32x16_bf16(a.s, b.s, acc, 0, 0, 0);
    }
}

// ---- segment runner: 4-chunk groups, register double-buffered B prefetch ----
template<int Q>
__device__ __forceinline__ void seg_run(int c0, int nG,
                                        const uint4* __restrict__ bpl,  // Bp + lane
                                        const float2v (&zr2)[16],
                                        const char* zbase, bool hi, f32x16& acc) {
    const uint4* p = bpl + (size_t)c0 * 64;
    uint4 cur[4] = {p[0], p[64], p[128], p[192]};
    int c = c0;
#pragma unroll 2
    for (int g = 0; g < nG - 1; ++g) {
        uint4 nxt[4] = {p[256], p[320], p[384], p[448]};
        chunk4<Q>(c, cur, zr2, zbase, hi, acc);
        cur[0] = nxt[0]; cur[1] = nxt[1]; cur[2] = nxt[2]; cur[3] = nxt[3];
        p += 256; c += 4;
    }
    chunk4<Q>(c, cur, zr2, zbase, hi, acc);
}

// ---- main: one wave per 32x32 output tile ----
__global__ __launch_bounds__(256, 2) void sindy_mfma(const float* __restrict__ z,
                                                     const float* __restrict__ Xi,
                                                     const float* __restrict__ Xi_mask,
                                                     const uint4* __restrict__ Bp,
                                                     float* __restrict__ out) {
    const int lane = threadIdx.x & 63;
    const int w = threadIdx.x >> 6;
    const int m = lane & 31;
    const int half = lane >> 5;
    const int wave = blockIdx.x * WPB + w;
    const long R = (long)wave * 32;

    __shared__ float zs[WPB][32][33];   // stride 33 -> p-reads conflict-free

    float2v zr2[16];
    const float4* z4 = (const float4*)(z + (R + m) * Z);
#pragma unroll
    for (int t = 0; t < 8; ++t) {
        float4 v = z4[t];
        zr2[2*t]   = float2v{v.x, v.y};
        zr2[2*t+1] = float2v{v.z, v.w};
    }
#pragma unroll
    for (int t = 0; t < 8; ++t) {
        zs[w][m][half * 16 + 2*t]     = zr2[half * 8 + t].x;
        zs[w][m][half * 16 + 2*t + 1] = zr2[half * 8 + t].y;
    }
    if (half == 0) zs[w][m][32] = 1.0f;   // z~[32] = 1.0 sentinel
    __syncthreads();

    const float bias = Xi[m] * Xi_mask[m];   // library row 0 (ones), col n = m
    f32x16 acc = {};
    const char* zbase = (const char*)&zs[w][m][0];
    const uint4* bpl = Bp + lane;
    const bool hi = (half != 0);

    seg_run<0>(  0,  9, bpl, zr2, zbase, hi, acc);
    seg_run<1>( 36, 21, bpl, zr2, zbase, hi, acc);
    seg_run<2>(120, 40, bpl, zr2, zbase, hi, acc);
    seg_run<3>(280, 68, bpl, zr2, zbase, hi, acc);

#pragma unroll
    for (int r = 0; r < 16; ++r) acc[r] += bias;

    float* orow = out + R * Z;
#pragma unroll
    for (int r = 0; r < 16; ++r) {
        int row = (r & 3) + 8 * (r >> 2) + 4 * half;
        orow[row * Z + m] = acc[r];
    }
}

extern "C" void kernel_launch(void* const* d_in, const int* in_sizes, int n_in,
                              void* d_out, int out_size, void* d_ws, size_t ws_size,
                              hipStream_t stream) {
    const float* z       = (const float*)d_in[0];
    const float* Xi      = (const float*)d_in[1];
    const float* Xi_mask = (const float*)d_in[2];
    // d_in[3]=z_mean, d_in[4]=z_std: unused by the reference
    float* out = (float*)d_out;
    uint4* Bp  = (uint4*)d_ws;   // NCHUNK*64*16 = 565,248 bytes

    int prep_threads = NCHUNK * 64;
    sindy_prep<<<(prep_threads + 255) / 256, 256, 0, stream>>>(Xi, Xi_mask, Bp, ws_size);
    sindy_mfma<<<NBLK, 256, 0, stream>>>(z, Xi, Xi_mask, Bp, out);
}

// Round 5
// 134.013 us; speedup vs baseline: 1.2166x; 1.2166x over previous
//
#include <hip/hip_runtime.h>

// SINDy: out[65536,32] = Theta(z)[65536,6545] @ (Xi*Xi_mask)[6545,32]
// Round-5 = Round-3 proven skeleton (lambda seg_run, rolled group loop,
// 4-chunk register double-buffer; VGPR 64, no scratch) + three changes:
//  - split-K inside the block: wave pair (kh0,kh1) shares one 32x32 tile;
//    kh0 = segments 0-2 (280 chunks), kh1 = segment 3 (272); kh1 parks acc
//    in LDS, kh0 combines+stores. Grid 1024 blocks -> 4 waves/SIMD.
//  - inner trim: u64 meta (1 s_load_dwordx2), v_pk_mul_f32 via float2,
//    cvt_pk_bf16_f32 pack (perm fallback). NO unroll-2, NO array params
//    (R4's spill lesson).
//  - prep with wave-uniform granule index (tid>>6) -> scalar table loads.
// MFMA 32x32x16_bf16 layouts (verified rounds 1-4):
//   A[m][k]: m=lane&31, k=(lane>>5)*8+jj
//   B[k][n]: n=lane&31, k=(lane>>5)*8+jj
//   C/D:     col=lane&31, row=(reg&3)+8*(reg>>2)+4*(lane>>5)

#define Z 32
#define ROWS 65536
#define NTILE (ROWS / 32)        // 2048 tiles
#define NBLK (NTILE / 2)         // 1024 blocks: 2 tiles x 2 k-halves = 4 waves

#define NCHUNK 552               // 36 + 84 + 160 + 272 (quarter-segments)
#define NGRAN (NCHUNK * 2)

typedef short short8 __attribute__((ext_vector_type(8)));
typedef float f32x16 __attribute__((ext_vector_type(16)));
typedef float float2v __attribute__((ext_vector_type(2)));

struct Sched {
    int nq[4];                       // chunks per quarter-segment
    unsigned long long m2[NCHUNK];   // lo32: granule0 (i*4)|(j*4)<<16 ; hi32: granule1
    short rt[NGRAN * 8];             // library row per (granule, jj), -1 = pad
};

constexpr Sched make_sched() {
    Sched s{};
    short gi[NGRAN] = {}, gj[NGRAN] = {};
    char gt[NGRAN] = {}, gq[NGRAN] = {};
    int tidx[32][32] = {}, pidx[32] = {};
    {
        int n = 0;
        for (int a = 0; a < 32; ++a)
            for (int b = a; b < 32; ++b) { tidx[a][b] = n; n += 32 - b; }
        for (int i = 0; i < 32; ++i) pidx[i] = i * 32 - i * (i - 1) / 2;
    }
    int g = 0;
    for (int q = 0; q < 4; ++q) {
        int g0 = g;
        // triples (a<=b): granule covers k in [8q,8q+8) for k>=b -> need b>>3 <= q
        for (int b = 0; b < 32; ++b)
            if ((b >> 3) <= q)
                for (int a = 0; a <= b; ++a) { gi[g]=(short)a; gj[g]=(short)b; gt[g]=0; gq[g]=(char)q; ++g; }
        // pairs (b,32): theta = z_b*z_k, valid k<=b -> need b>>3 >= q
        for (int b = 0; b < 32; ++b)
            if ((b >> 3) >= q) { gi[g]=(short)b; gj[g]=32; gt[g]=1; gq[g]=(char)q; ++g; }
        // linear: theta = z_k
        gi[g]=32; gj[g]=32; gt[g]=2; gq[g]=(char)q; ++g;
        // pad quarter to a multiple of 8 granules (4 chunks)
        while ((g - g0) & 7) { gi[g]=32; gj[g]=32; gt[g]=3; gq[g]=(char)q; ++g; }
        s.nq[q] = (g - g0) / 2;
    }
    for (int c = 0; c < NCHUNK; ++c) {
        unsigned lo = ((unsigned)gi[2*c]   * 4u) | (((unsigned)gj[2*c]   * 4u) << 16);
        unsigned hi = ((unsigned)gi[2*c+1] * 4u) | (((unsigned)gj[2*c+1] * 4u) << 16);
        s.m2[c] = (unsigned long long)lo | ((unsigned long long)hi << 32);
    }
    for (int gg = 0; gg < NGRAN; ++gg) {
        int i = gi[gg], j = gj[gg], ty = gt[gg], q = gq[gg];
        for (int jj = 0; jj < 8; ++jj) {
            int k = 8 * q + jj, row = -1;
            if (ty == 0)      { if (k >= j) row = 561 + tidx[i][j] + (k - j); }   // triple (i,j,k)
            else if (ty == 1) { if (k <= i) row = 33 + pidx[k] + (i - k); }       // pair (k,i)
            else if (ty == 2) { row = 1 + k; }                                    // linear z_k
            s.rt[gg * 8 + jj] = (short)row;
        }
    }
    return s;
}
constexpr Sched S = make_sched();
static_assert(S.nq[0] == 36 && S.nq[1] == 84 && S.nq[2] == 160 && S.nq[3] == 272, "chunk counts");

__device__ __forceinline__ unsigned pack_bf16(float s0, float s1) {
#if __has_builtin(__builtin_amdgcn_cvt_pk_bf16_f32)
    return __builtin_bit_cast(unsigned, __builtin_amdgcn_cvt_pk_bf16_f32(s0, s1));
#else
    unsigned b0 = __builtin_bit_cast(unsigned, s0) + 0x8000u;
    unsigned b1 = __builtin_bit_cast(unsigned, s1) + 0x8000u;
    return __builtin_amdgcn_perm(b1, b0, 0x07060302u);   // lo16=s0, hi16=s1
#endif
}

// ---- prep: pack Xi_eff (bf16 RNE) into granule-ordered B fragments ----
// One wave per granule (g = tid>>6 is wave-uniform -> scalar table loads).
// Lane: col n = lane&31, rep = lane>>5 covers slots 4*rep..4*rep+3 (one uint2).
__global__ void sindy_prep(const float* __restrict__ Xi,
                           const float* __restrict__ Xi_mask,
                           uint2* __restrict__ Bp2, size_t ws_size) {
    int tid = blockIdx.x * blockDim.x + threadIdx.x;
    if (tid >= NGRAN * 64) return;
    int g = tid >> 6;            // wave-uniform
    int lane = tid & 63;
    int n = lane & 31, rep = lane >> 5;
    const short* rt = &S.rt[g * 8 + 4 * rep];
    unsigned v[4];
#pragma unroll
    for (int jj = 0; jj < 4; ++jj) {
        int row = rt[jj];
        float f = 0.0f;
        if (row >= 0) f = Xi[row * Z + n] * Xi_mask[row * Z + n];
        unsigned u = __builtin_bit_cast(unsigned, f);
        v[jj] = (u + 0x7FFFu + ((u >> 16) & 1u)) >> 16;   // RNE to bf16
    }
    int c = g >> 1, h = g & 1;
    size_t idx = ((size_t)c * 64 + h * 32 + n) * 2 + rep;
    if ((idx + 1) * 8 <= ws_size)   // safety
        Bp2[idx] = uint2{v[0] | (v[1] << 16), v[2] | (v[3] << 16)};
}

// ---- segment runner: 4-chunk groups, register double-buffered B prefetch ----
// (R3-proven structure: lambda body, rolled group loop, scalar b0..b3 args)
template<int Q>
__device__ __forceinline__ void seg_run(int c0, int nG,
                                        const uint4* __restrict__ bpl,  // Bp + lane
                                        const float2v (&zr2)[16],
                                        const char* zbase, bool hi, f32x16& acc) {
    const uint4* p = bpl + (size_t)c0 * 64;
    uint4 cur0 = p[0], cur1 = p[64], cur2 = p[128], cur3 = p[192];
    int c = c0;
    auto body = [&](uint4 b0, uint4 b1, uint4 b2, uint4 b3) {
        const uint4 bb[4] = {b0, b1, b2, b3};
#pragma unroll
        for (int i = 0; i < 4; ++i) {
            unsigned long long m2 = S.m2[c + i];            // uniform -> s_load_dwordx2
            unsigned mw = hi ? (unsigned)(m2 >> 32) : (unsigned)m2;
            float zi = *(const float*)(zbase + (mw & 0xFFFFu));
            float zj = *(const float*)(zbase + (mw >> 16));
            float pp = zi * zj;
            float2v p2; p2.x = pp; p2.y = pp;
            union { unsigned u[4]; short8 s; } a;
#pragma unroll
            for (int r = 0; r < 4; ++r) {
                float2v t = p2 * zr2[4 * Q + r];            // v_pk_mul_f32
                a.u[r] = pack_bf16(t.x, t.y);
            }
            union { uint4 v; short8 s; } b; b.v = bb[i];
            acc = __builtin_amdgcn_mfma_f32_32x32x16_bf16(a.s, b.s, acc, 0, 0, 0);
        }
        c += 4;
    };
    for (int g = 0; g < nG - 1; ++g) {
        const uint4* pn = p + 256;
        uint4 n0 = pn[0], n1 = pn[64], n2 = pn[128], n3 = pn[192];
        body(cur0, cur1, cur2, cur3);
        cur0 = n0; cur1 = n1; cur2 = n2; cur3 = n3;
        p = pn;
    }
    body(cur0, cur1, cur2, cur3);
}

// ---- main: 4 waves/block = 2 tiles x 2 k-halves; LDS combine ----
__global__ __launch_bounds__(256, 4) void sindy_mfma(const float* __restrict__ z,
                                                     const float* __restrict__ Xi,
                                                     const float* __restrict__ Xi_mask,
                                                     const uint4* __restrict__ Bp,
                                                     float* __restrict__ out) {
    const int lane = threadIdx.x & 63;
    const int w = threadIdx.x >> 6;
    const int tib = w >> 1;          // tile-in-block 0/1
    const int kh = w & 1;            // k-half: 0 = segs 0-2, 1 = seg 3
    const int m = lane & 31;
    const int half = lane >> 5;
    const int tile = blockIdx.x * 2 + tib;
    const long R = (long)tile * 32;

    __shared__ float zs[2][32][33];  // stride 33 -> p-reads conflict-free
    __shared__ float cs[2][32][32];  // kh1's partial accumulator

    float2v zr2[16];
    const float4* z4 = (const float4*)(z + (R + m) * Z);
#pragma unroll
    for (int t = 0; t < 8; ++t) {
        float4 v = z4[t];
        zr2[2*t]   = float2v{v.x, v.y};
        zr2[2*t+1] = float2v{v.z, v.w};
    }
    if (kh == 0) {
#pragma unroll
        for (int t = 0; t < 8; ++t) {
            zs[tib][m][half * 16 + 2*t]     = zr2[half * 8 + t].x;
            zs[tib][m][half * 16 + 2*t + 1] = zr2[half * 8 + t].y;
        }
        if (half == 0) zs[tib][m][32] = 1.0f;   // z~[32] = 1.0 sentinel
    }
    __syncthreads();

    f32x16 acc = {};
    const char* zbase = (const char*)&zs[tib][m][0];
    const uint4* bpl = Bp + lane;
    const bool hi = (half != 0);

    if (kh == 0) {
        seg_run<0>(  0,  9, bpl, zr2, zbase, hi, acc);
        seg_run<1>( 36, 21, bpl, zr2, zbase, hi, acc);
        seg_run<2>(120, 40, bpl, zr2, zbase, hi, acc);
    } else {
        seg_run<3>(280, 68, bpl, zr2, zbase, hi, acc);
        // park partial in LDS (col=m consecutive per half-wave -> conflict-free)
#pragma unroll
        for (int r = 0; r < 16; ++r) {
            int row = (r & 3) + 8 * (r >> 2) + 4 * half;
            cs[tib][row][m] = acc[r];
        }
    }
    __syncthreads();

    if (kh == 0) {
        const float bias = Xi[m] * Xi_mask[m];   // library row 0 (ones), col n = m
        float* orow = out + R * Z;
#pragma unroll
        for (int r = 0; r < 16; ++r) {
            int row = (r & 3) + 8 * (r >> 2) + 4 * half;
            orow[row * Z + m] = acc[r] + cs[tib][row][m] + bias;
        }
    }
}

extern "C" void kernel_launch(void* const* d_in, const int* in_sizes, int n_in,
                              void* d_out, int out_size, void* d_ws, size_t ws_size,
                              hipStream_t stream) {
    const float* z       = (const float*)d_in[0];
    const float* Xi      = (const float*)d_in[1];
    const float* Xi_mask = (const float*)d_in[2];
    // d_in[3]=z_mean, d_in[4]=z_std: unused by the reference
    float* out = (float*)d_out;
    uint4* Bp  = (uint4*)d_ws;   // NCHUNK*64*16 = 565,248 bytes

    int prep_threads = NGRAN * 64;
    sindy_prep<<<(prep_threads + 255) / 256, 256, 0, stream>>>(Xi, Xi_mask, (uint2*)d_ws, ws_size);
    sindy_mfma<<<NBLK, 256, 0, stream>>>(z, Xi, Xi_mask, Bp, out);
}

// Round 6
// 131.567 us; speedup vs baseline: 1.2392x; 1.0186x over previous
//
#include <hip/hip_runtime.h>

// SINDy: out[65536,32] = Theta(z)[65536,6545] @ (Xi*Xi_mask)[6545,32]
// Round-6 = Round-5 skeleton (split-K 4 waves/block, 552-chunk schedule,
// B pre-packed in ws, 4-chunk B register double-buffer) with the per-chunk
// dependency chain broken:
//  - granule meta (byte-offset pairs) in LDS, indexed per-lane by half ->
//    no s_load/cndmask in the hot path
//  - 2-stage software pipeline for pair products: mg read 2 SGs ahead,
//    zi/zj ds_reads 1 SG ahead, muls after the MFMA block (scalars only)
//  - kh balance 276/276, contiguous B stream per wave
// MFMA 32x32x16_bf16 layouts (verified rounds 1-5):
//   A[m][k]: m=lane&31, k=(lane>>5)*8+jj
//   B[k][n]: n=lane&31, k=(lane>>5)*8+jj
//   C/D:     col=lane&31, row=(reg&3)+8*(reg>>2)+4*(lane>>5)

#define Z 32
#define ROWS 65536
#define NTILE (ROWS / 32)        // 2048 tiles
#define NBLK (NTILE / 2)         // 1024 blocks: 2 tiles x 2 k-halves = 4 waves

#define NCHUNK 552               // 36 + 84 + 160 + 272 (quarter-segments, x4)
#define NGRAN (NCHUNK * 2)
#define KH_SPLIT 276             // kh0: [0,276), kh1: [276,552)

typedef short short8 __attribute__((ext_vector_type(8)));
typedef float f32x16 __attribute__((ext_vector_type(16)));
typedef float float2v __attribute__((ext_vector_type(2)));

struct Sched {
    int nq[4];                 // chunks per quarter-segment
    unsigned mg[NGRAN];        // per-granule (i*4) | (j*4)<<16 byte offsets
    short rt[NGRAN * 8];       // library row per (granule, jj), -1 = pad
};

constexpr Sched make_sched() {
    Sched s{};
    short gi[NGRAN] = {}, gj[NGRAN] = {};
    char gt[NGRAN] = {}, gq[NGRAN] = {};
    int tidx[32][32] = {}, pidx[32] = {};
    {
        int n = 0;
        for (int a = 0; a < 32; ++a)
            for (int b = a; b < 32; ++b) { tidx[a][b] = n; n += 32 - b; }
        for (int i = 0; i < 32; ++i) pidx[i] = i * 32 - i * (i - 1) / 2;
    }
    int g = 0;
    for (int q = 0; q < 4; ++q) {
        int g0 = g;
        // triples (a<=b): granule covers k in [8q,8q+8) for k>=b -> need b>>3 <= q
        for (int b = 0; b < 32; ++b)
            if ((b >> 3) <= q)
                for (int a = 0; a <= b; ++a) { gi[g]=(short)a; gj[g]=(short)b; gt[g]=0; gq[g]=(char)q; ++g; }
        // pairs (b,32): theta = z_b*z_k, valid k<=b -> need b>>3 >= q
        for (int b = 0; b < 32; ++b)
            if ((b >> 3) >= q) { gi[g]=(short)b; gj[g]=32; gt[g]=1; gq[g]=(char)q; ++g; }
        // linear: theta = z_k
        gi[g]=32; gj[g]=32; gt[g]=2; gq[g]=(char)q; ++g;
        // pad quarter to a multiple of 8 granules (4 chunks)
        while ((g - g0) & 7) { gi[g]=32; gj[g]=32; gt[g]=3; gq[g]=(char)q; ++g; }
        s.nq[q] = (g - g0) / 2;
    }
    for (int gg = 0; gg < NGRAN; ++gg) {
        s.mg[gg] = ((unsigned)gi[gg] * 4u) | (((unsigned)gj[gg] * 4u) << 16);
        int i = gi[gg], j = gj[gg], ty = gt[gg], q = gq[gg];
        for (int jj = 0; jj < 8; ++jj) {
            int k = 8 * q + jj, row = -1;
            if (ty == 0)      { if (k >= j) row = 561 + tidx[i][j] + (k - j); }   // triple (i,j,k)
            else if (ty == 1) { if (k <= i) row = 33 + pidx[k] + (i - k); }       // pair (k,i)
            else if (ty == 2) { row = 1 + k; }                                    // linear z_k
            s.rt[gg * 8 + jj] = (short)row;
        }
    }
    return s;
}
constexpr Sched S = make_sched();
static_assert(S.nq[0] == 36 && S.nq[1] == 84 && S.nq[2] == 160 && S.nq[3] == 272, "chunk counts");

__device__ __forceinline__ unsigned pack_bf16(float s0, float s1) {
#if __has_builtin(__builtin_amdgcn_cvt_pk_bf16_f32)
    return __builtin_bit_cast(unsigned, __builtin_amdgcn_cvt_pk_bf16_f32(s0, s1));
#else
    unsigned b0 = __builtin_bit_cast(unsigned, s0) + 0x8000u;
    unsigned b1 = __builtin_bit_cast(unsigned, s1) + 0x8000u;
    return __builtin_amdgcn_perm(b1, b0, 0x07060302u);   // lo16=s0, hi16=s1
#endif
}

// ---- prep: pack Xi_eff (bf16 RNE) into granule-ordered B fragments ----
// One wave per granule (g = tid>>6 wave-uniform -> scalar table loads).
// Lane: col n = lane&31, rep = lane>>5 covers slots 4*rep..4*rep+3 (one uint2).
__global__ void sindy_prep(const float* __restrict__ Xi,
                           const float* __restrict__ Xi_mask,
                           uint2* __restrict__ Bp2, size_t ws_size) {
    int tid = blockIdx.x * blockDim.x + threadIdx.x;
    if (tid >= NGRAN * 64) return;
    int g = tid >> 6;            // wave-uniform
    int lane = tid & 63;
    int n = lane & 31, rep = lane >> 5;
    const short* rt = &S.rt[g * 8 + 4 * rep];
    unsigned v[4];
#pragma unroll
    for (int jj = 0; jj < 4; ++jj) {
        int row = rt[jj];
        float f = 0.0f;
        if (row >= 0) f = Xi[row * Z + n] * Xi_mask[row * Z + n];
        unsigned u = __builtin_bit_cast(unsigned, f);
        v[jj] = (u + 0x7FFFu + ((u >> 16) & 1u)) >> 16;   // RNE to bf16
    }
    int c = g >> 1, h = g & 1;
    size_t idx = ((size_t)c * 64 + h * 32 + n) * 2 + rep;
    if ((idx + 1) * 8 <= ws_size)   // safety
        Bp2[idx] = uint2{v[0] | (v[1] << 16), v[2] | (v[3] << 16)};
}

// pair product from LDS z-row via packed byte offsets
__device__ __forceinline__ float pprod(const char* zb, unsigned mw) {
    float zi = *(const float*)(zb + (mw & 0xFFFFu));
    float zj = *(const float*)(zb + (mw >> 16));
    return zi * zj;
}

// ---- segment runner: SG = 4 chunks; 2-stage phase-A pipeline + B dbuf ----
template<int Q, bool LAST>
__device__ __forceinline__ void seg_run(int cbeg, int nSG,
                                        const uint4*& p,
                                        uint4& cur0, uint4& cur1, uint4& cur2, uint4& cur3,
                                        const unsigned* __restrict__ mgh,  // &mg_sh[half]
                                        const char* __restrict__ zrowc,    // &zs[tib][m][0]
                                        f32x16& acc) {
    // this quarter's z values (static LDS offsets, broadcast reads)
    const float* zrow = (const float*)zrowc;
    float2v zq0, zq1, zq2, zq3;
    zq0.x = zrow[8*Q+0]; zq0.y = zrow[8*Q+1];
    zq1.x = zrow[8*Q+2]; zq1.y = zrow[8*Q+3];
    zq2.x = zrow[8*Q+4]; zq2.y = zrow[8*Q+5];
    zq3.x = zrow[8*Q+6]; zq3.y = zrow[8*Q+7];

    auto chunk = [&](float pp, const uint4& bv) {
        float2v p2; p2.x = pp; p2.y = pp;
        union { unsigned u[4]; short8 sv; } a;
        float2v t0 = p2 * zq0; a.u[0] = pack_bf16(t0.x, t0.y);
        float2v t1 = p2 * zq1; a.u[1] = pack_bf16(t1.x, t1.y);
        float2v t2 = p2 * zq2; a.u[2] = pack_bf16(t2.x, t2.y);
        float2v t3 = p2 * zq3; a.u[3] = pack_bf16(t3.x, t3.y);
        union { uint4 v; short8 sv; } b; b.v = bv;
        acc = __builtin_amdgcn_mfma_f32_32x32x16_bf16(a.sv, b.sv, acc, 0, 0, 0);
    };

    // prologue: products for SG 0 (cold), mg words for SG 1
    const unsigned* mg0 = mgh + 2 * cbeg;
    float pC0 = pprod(zrowc, mg0[0]);
    float pC1 = pprod(zrowc, mg0[2]);
    float pC2 = pprod(zrowc, mg0[4]);
    float pC3 = pprod(zrowc, mg0[6]);
    unsigned w10 = 0, w11 = 0, w12 = 0, w13 = 0;
    if (nSG > 1) {
        const unsigned* mg1 = mgh + 2 * (cbeg + 4);
        w10 = mg1[0]; w11 = mg1[2]; w12 = mg1[4]; w13 = mg1[6];
    }

    for (int s = 0; s < nSG; ++s) {
        // stage 2: mg words for SG s+2
        unsigned w20 = 0, w21 = 0, w22 = 0, w23 = 0;
        if (s + 2 < nSG) {
            const unsigned* mg2 = mgh + 2 * (cbeg + 4 * (s + 2));
            w20 = mg2[0]; w21 = mg2[2]; w22 = mg2[4]; w23 = mg2[6];
        }
        // stage 1: z loads for SG s+1 (issued before the MFMA block)
        float zi0=0,zj0=0,zi1=0,zj1=0,zi2=0,zj2=0,zi3=0,zj3=0;
        bool more = (s + 1 < nSG);
        if (more) {
            zi0 = *(const float*)(zrowc + (w10 & 0xFFFFu)); zj0 = *(const float*)(zrowc + (w10 >> 16));
            zi1 = *(const float*)(zrowc + (w11 & 0xFFFFu)); zj1 = *(const float*)(zrowc + (w11 >> 16));
            zi2 = *(const float*)(zrowc + (w12 & 0xFFFFu)); zj2 = *(const float*)(zrowc + (w12 >> 16));
            zi3 = *(const float*)(zrowc + (w13 & 0xFFFFu)); zj3 = *(const float*)(zrowc + (w13 >> 16));
        }
        // B prefetch for next SG
        bool pref = !(LAST && s == nSG - 1);
        uint4 n0, n1, n2, n3;
        if (pref) { n0 = p[256]; n1 = p[320]; n2 = p[384]; n3 = p[448]; }
        // MFMA block for SG s
        chunk(pC0, cur0); chunk(pC1, cur1); chunk(pC2, cur2); chunk(pC3, cur3);
        // retire pipeline stages
        if (more) {
            pC0 = zi0 * zj0; pC1 = zi1 * zj1; pC2 = zi2 * zj2; pC3 = zi3 * zj3;
            w10 = w20; w11 = w21; w12 = w22; w13 = w23;
        }
        if (pref) { cur0 = n0; cur1 = n1; cur2 = n2; cur3 = n3; p += 256; }
    }
}

// ---- main: 4 waves/block = 2 tiles x 2 k-halves; LDS combine ----
__global__ __launch_bounds__(256, 4) void sindy_mfma(const float* __restrict__ z,
                                                     const float* __restrict__ Xi,
                                                     const float* __restrict__ Xi_mask,
                                                     const uint4* __restrict__ Bp,
                                                     float* __restrict__ out) {
    const int lane = threadIdx.x & 63;
    const int w = threadIdx.x >> 6;
    const int tib = w >> 1;          // tile-in-block 0/1
    const int kh = w & 1;            // k-half: 0 = chunks [0,276), 1 = [276,552)
    const int m = lane & 31;
    const int half = lane >> 5;
    const int tile = blockIdx.x * 2 + tib;
    const long R = (long)tile * 32;

    __shared__ float zs[2][32][33];      // stride 33 -> conflict-free dyn reads
    __shared__ float cs[2][32][32];      // kh1's partial accumulator
    __shared__ unsigned mg_sh[NGRAN];    // granule offset pairs (4.4 KB)

    for (int t = threadIdx.x; t < NGRAN; t += 256) mg_sh[t] = S.mg[t];

    if (kh == 0) {   // only kh0 loads z (halves global z traffic)
        const float4* z4 = (const float4*)(z + (R + m) * Z);
#pragma unroll
        for (int t = 0; t < 8; ++t) {
            float4 v = z4[t];
            zs[tib][m][4*t+0] = v.x; zs[tib][m][4*t+1] = v.y;
            zs[tib][m][4*t+2] = v.z; zs[tib][m][4*t+3] = v.w;
        }
        if (half == 0) zs[tib][m][32] = 1.0f;   // z~[32] = 1.0 sentinel
    }

    // first B group (prep data is stream-ordered; barrier below drains vmcnt)
    const int cbeg = kh ? KH_SPLIT : 0;
    const uint4* p = Bp + lane + (size_t)cbeg * 64;
    uint4 cur0 = p[0], cur1 = p[64], cur2 = p[128], cur3 = p[192];

    __syncthreads();

    f32x16 acc = {};
    const char* zrowc = (const char*)&zs[tib][m][0];
    const unsigned* mgh = mg_sh + half;

    if (kh == 0) {
        seg_run<0, false>(  0,  9, p, cur0, cur1, cur2, cur3, mgh, zrowc, acc);
        seg_run<1, false>( 36, 21, p, cur0, cur1, cur2, cur3, mgh, zrowc, acc);
        seg_run<2, true >(120, 39, p, cur0, cur1, cur2, cur3, mgh, zrowc, acc);
    } else {
        seg_run<2, false>(276,  1, p, cur0, cur1, cur2, cur3, mgh, zrowc, acc);
        seg_run<3, true >(280, 68, p, cur0, cur1, cur2, cur3, mgh, zrowc, acc);
        // park partial in LDS (stride 32: same bank both halves -> 2-way, free)
#pragma unroll
        for (int r = 0; r < 16; ++r) {
            int row = (r & 3) + 8 * (r >> 2) + 4 * half;
            cs[tib][row][m] = acc[r];
        }
    }
    __syncthreads();

    if (kh == 0) {
        const float bias = Xi[m] * Xi_mask[m];   // library row 0 (ones), col n = m
        float* orow = out + R * Z;
#pragma unroll
        for (int r = 0; r < 16; ++r) {
            int row = (r & 3) + 8 * (r >> 2) + 4 * half;
            orow[row * Z + m] = acc[r] + cs[tib][row][m] + bias;
        }
    }
}

extern "C" void kernel_launch(void* const* d_in, const int* in_sizes, int n_in,
                              void* d_out, int out_size, void* d_ws, size_t ws_size,
                              hipStream_t stream) {
    const float* z       = (const float*)d_in[0];
    const float* Xi      = (const float*)d_in[1];
    const float* Xi_mask = (const float*)d_in[2];
    // d_in[3]=z_mean, d_in[4]=z_std: unused by the reference
    float* out = (float*)d_out;
    uint4* Bp  = (uint4*)d_ws;   // NCHUNK*64*16 = 565,248 bytes

    int prep_threads = NGRAN * 64;
    sindy_prep<<<(prep_threads + 255) / 256, 256, 0, stream>>>(Xi, Xi_mask, (uint2*)d_ws, ws_size);
    sindy_mfma<<<NBLK, 256, 0, stream>>>(z, Xi, Xi_mask, Bp, out);
}